// Round 1
// 259.733 us; speedup vs baseline: 1.0344x; 1.0344x over previous
//
#include <hip/hip_runtime.h>
#include <hip/hip_fp16.h>

#define N_NODES 100000
#define N_EDGES 1600000
#define IN_F 128
#define HID_F 64
#define CLS_F 32

#define NBKT 512                 // buckets of 196 dst nodes each
#define BKT_NODES 196
#define EPB 16384                // edges per partition block
#define NBLK 98                  // ceil(1600000/16384)
#define NVAL (NBKT * NBLK)       // 50176
#define CAPB 5120                // fixed padded csr region per bucket (mean ~3900, >16 sigma)

typedef short s8v __attribute__((ext_vector_type(8)));
typedef float f4v __attribute__((ext_vector_type(4)));

__device__ __forceinline__ unsigned short f2b(float f) {
    union { float f; unsigned i; } c; c.f = f;
    unsigned r = c.i + 0x7FFFu + ((c.i >> 16) & 1u);   // round-nearest-even
    return (unsigned short)(r >> 16);
}
__device__ __forceinline__ unsigned short f2h(float f) {
    return __half_as_ushort(__float2half_rn(f));
}

// ---------------------------------------------------------------------------
// CSR build: bucket histogram -> scan -> scatter -> per-bucket counting sort.
// v6: node segments padded to multiple of 8 with dummy index N_NODES (whose
// feature rows are zero), so gathers need no masking and index quads are
// 16B-aligned -> s_load_dwordx4.
// ---------------------------------------------------------------------------

__global__ __launch_bounds__(256) void bucketA_kernel(const int* __restrict__ dst,
                                                      int* __restrict__ bh) {
    __shared__ int h[NBKT];
    for (int i = threadIdx.x; i < NBKT; i += 256) h[i] = 0;
    __syncthreads();
    int e0 = blockIdx.x * EPB;
    int e1 = min(e0 + EPB, N_EDGES);
    for (int e = e0 + threadIdx.x; e < e1; e += 256)
        atomicAdd(&h[dst[e] / BKT_NODES], 1);
    __syncthreads();
    for (int i = threadIdx.x; i < NBKT; i += 256)
        bh[i * NBLK + blockIdx.x] = h[i];
}

__global__ __launch_bounds__(1024) void scan_hist_kernel(int* __restrict__ bh) {
    __shared__ int wsum[16];
    const int CH = (NVAL + 1023) / 1024;   // 49
    int t = threadIdx.x;
    int base = t * CH;
    int v[CH];
    int local = 0;
#pragma unroll
    for (int i = 0; i < CH; i++) {
        int idx = base + i;
        int x = (idx < NVAL) ? bh[idx] : 0;
        v[i] = local;
        local += x;
    }
    int lane = t & 63, w = t >> 6;
    int s = local;
#pragma unroll
    for (int d = 1; d < 64; d <<= 1) {
        int u = __shfl_up(s, d);
        if (lane >= d) s += u;
    }
    if (lane == 63) wsum[w] = s;
    __syncthreads();
    int wbase = 0;
    for (int i = 0; i < w; i++) wbase += wsum[i];
    int tbase = wbase + s - local;
#pragma unroll
    for (int i = 0; i < CH; i++) {
        int idx = base + i;
        if (idx < NVAL) bh[idx] = tbase + v[i];
    }
}

__global__ __launch_bounds__(256) void bucketB_kernel(const int* __restrict__ src,
                                                      const int* __restrict__ dst,
                                                      const int* __restrict__ bhScan,
                                                      unsigned* __restrict__ bkt) {
    __shared__ int cur[NBKT];
    for (int i = threadIdx.x; i < NBKT; i += 256)
        cur[i] = bhScan[i * NBLK + blockIdx.x];
    __syncthreads();
    int e0 = blockIdx.x * EPB;
    int e1 = min(e0 + EPB, N_EDGES);
    for (int e = e0 + threadIdx.x; e < e1; e += 256) {
        int d = dst[e];
        int g = d / BKT_NODES;
        unsigned pk = ((unsigned)(d - g * BKT_NODES) << 17) | (unsigned)src[e];
        int pos = atomicAdd(&cur[g], 1);
        bkt[pos] = pk;
    }
}

__global__ __launch_bounds__(256) void sort_bucket_kernel(const int* __restrict__ bhScan,
                                                          const unsigned* __restrict__ bkt,
                                                          int* __restrict__ csr,
                                                          int* __restrict__ off,
                                                          int* __restrict__ endp,
                                                          float* __restrict__ dinv) {
    __shared__ int hist[BKT_NODES];
    __shared__ int loff[BKT_NODES];    // mutated by scatter atomics
    __shared__ int loffB[BKT_NODES];   // stable padded bases
    __shared__ int wt[4];
    __shared__ int csrS[CAPB];
    int b = blockIdx.x;
    int t = threadIdx.x;
    int s0 = bhScan[b * NBLK];
    int s1 = (b < NBKT - 1) ? bhScan[(b + 1) * NBLK] : N_EDGES;
    int nE = s1 - s0;

    for (int i = t; i < BKT_NODES; i += 256) hist[i] = 0;
    __syncthreads();
    for (int i = t; i < nE; i += 256)
        atomicAdd(&hist[bkt[s0 + i] >> 17], 1);
    __syncthreads();

    // exclusive scan of PADDED per-node sizes (pad to multiple of 8)
    int h0 = 0, h1 = 0;
    if (t < 98) { h0 = hist[2 * t]; h1 = hist[2 * t + 1]; }
    int p0 = (h0 + 7) & ~7;
    int p1 = (h1 + 7) & ~7;
    int sum = p0 + p1;
    int lane = t & 63, w = t >> 6;
    int s = sum;
#pragma unroll
    for (int d = 1; d < 64; d <<= 1) {
        int u = __shfl_up(s, d);
        if (lane >= d) s += u;
    }
    if (lane == 63) wt[w] = s;
    __syncthreads();
    int wbase = 0;
    for (int i = 0; i < w; i++) wbase += wt[i];
    int excl = wbase + s - sum;
    if (t < 98) {
        loff[2 * t] = excl;         loffB[2 * t] = excl;
        loff[2 * t + 1] = excl + p0; loffB[2 * t + 1] = excl + p0;
    }
    __syncthreads();

    for (int j = t; j < BKT_NODES; j += 256) {
        int n = b * BKT_NODES + j;
        if (n < N_NODES) {
            int c = hist[j];
            int o = b * CAPB + loff[j];
            off[n] = o;
            endp[n] = o + ((c + 7) & ~7);          // padded length
            dinv[n] = rsqrtf((float)(c + 1));
        }
    }
    __syncthreads();

    // scatter into padded staging (positions always < CAPB by construction)
    for (int i = t; i < nE; i += 256) {
        unsigned pk = bkt[s0 + i];
        int dl = (int)(pk >> 17);
        int p = atomicAdd(&loff[dl], 1);
        csrS[p] = (int)(pk & 0x1FFFFu);
    }
    __syncthreads();

    // fill pad slots with dummy node id (zero feature row)
    for (int j = t; j < BKT_NODES; j += 256) {
        int c = hist[j];
        int bse = loffB[j];
        int pe = bse + ((c + 7) & ~7);
        for (int p = bse + c; p < pe; p++) csrS[p] = N_NODES;
    }
    __syncthreads();

    int padTot = wt[0] + wt[1] + wt[2] + wt[3];
    for (int i = t; i < padTot; i += 256) csr[b * CAPB + i] = csrS[i];
}

// ---------------------------------------------------------------------------
// layer 1 GEMM via MFMA bf16; output now fp16 (better precision than bf16),
// also writes zero row at index N_NODES (dummy target for csr padding).
// ---------------------------------------------------------------------------
#define XBM 64
__global__ __launch_bounds__(256) void xw1_kernel(const float* __restrict__ x,
                                                  const float* __restrict__ W1,
                                                  const float* __restrict__ dinv,
                                                  unsigned short* __restrict__ y1h) {
    __shared__ __align__(16) unsigned short Wb[16 * 64 * 8];   // 16 KB, B-frag packed
    __shared__ __align__(16) unsigned short xb[XBM][IN_F + 8]; // 17 KB

    int tid = threadIdx.x;

    for (int i = tid; i < IN_F * HID_F; i += 256) {
        int k = i >> 6, n = i & 63;
        int kc = k >> 5, kw = k & 31;
        int nt = n >> 4, nl = n & 15;
        int quad = kw >> 3, j = kw & 7;
        Wb[(((kc * 4 + nt) * 64) + quad * 16 + nl) * 8 + j] = f2b(W1[i]);
    }

    int nodeBase = blockIdx.x * XBM;
    {
        int snl = tid >> 2;
        int sk0 = (tid & 3) * 32;
        int n = nodeBase + snl;
#pragma unroll
        for (int kk = 0; kk < 32; kk += 4) {
            float4 v = make_float4(0.f, 0.f, 0.f, 0.f);
            if (n < N_NODES) v = *(const float4*)(x + (size_t)n * IN_F + sk0 + kk);
            ushort4 o;
            o.x = f2b(v.x); o.y = f2b(v.y); o.z = f2b(v.z); o.w = f2b(v.w);
            *(ushort4*)(&xb[snl][sk0 + kk]) = o;
        }
    }
    __syncthreads();

    int wave = tid >> 6, lane = tid & 63;
    int quad = lane >> 4, l15 = lane & 15;
    int rowBase = wave * 16;

    f4v acc[4];
#pragma unroll
    for (int i = 0; i < 4; i++) acc[i] = (f4v){0.f, 0.f, 0.f, 0.f};

#pragma unroll
    for (int kc = 0; kc < 4; kc++) {
        s8v a = *(const s8v*)(&xb[rowBase + l15][kc * 32 + quad * 8]);
#pragma unroll
        for (int nt = 0; nt < 4; nt++) {
            s8v b = *(const s8v*)(&Wb[((kc * 4 + nt) * 64 + lane) * 8]);
            acc[nt] = __builtin_amdgcn_mfma_f32_16x16x32_bf16(a, b, acc[nt], 0, 0, 0);
        }
    }

    float dv[4];
    int n0 = nodeBase + rowBase + quad * 4;
#pragma unroll
    for (int r = 0; r < 4; r++)
        dv[r] = (n0 + r < N_NODES) ? dinv[n0 + r] : 0.f;
#pragma unroll
    for (int nt = 0; nt < 4; nt++) {
#pragma unroll
        for (int r = 0; r < 4; r++) {
            int n = n0 + r;
            if (n < N_NODES + 1)    // row N_NODES written as zeros (dv=0)
                y1h[(size_t)n * HID_F + nt * 16 + l15] = f2h(acc[nt][r] * dv[r]);
        }
    }
}

// ---------------------------------------------------------------------------
// gather1 + layer2 fused, v3: 2 nodes per wave. Neighbor indices come in via
// s_load_dwordx4 (uniform, padded, aligned) -> no per-edge ds_bpermute, no
// divergent trip counts. Phase A: all 64 lanes aggregate node A (lanes 0-31
// take even positions, 32-63 odd); phase B likewise; one shfl_xor(32) combine
// per accumulator. Epilogue (h @ W2 column dot via 32-step shfl) unchanged.
// ---------------------------------------------------------------------------
__global__ __launch_bounds__(256) void gather1_fused_kernel(
        const int* __restrict__ off, const int* __restrict__ endp,
        const int* __restrict__ csr, const unsigned short* __restrict__ y1h,
        const float* __restrict__ dinv, const float* __restrict__ W2,
        const float* __restrict__ b1, unsigned short* __restrict__ y2h) {
    int tid = threadIdx.x;
    int wv = __builtin_amdgcn_readfirstlane(tid >> 6);
    int wave = blockIdx.x * 4 + wv;            // wave-uniform
    int nA = wave * 2;
    int lane = tid & 63;
    int half = lane >> 5;
    int cl = lane & 31;
    int k2 = 2 * cl;

    int offA = off[nA], offB = off[nA + 1];    // s_load (uniform)
    int lenA = endp[nA] - offA;                // multiple of 8
    int lenB = endp[nA + 1] - offB;
    const int* csA = csr + offA;
    const int* csB = csr + offB;
    const unsigned* y1u = (const unsigned*)y1h;

    int node = nA + half;
    unsigned su = y1u[(size_t)node * 32 + cl];     // self row (2 fp16)
    union { unsigned u; __half2 h; } sc; sc.u = su;
    float sl = __half2float(sc.h.x), sh = __half2float(sc.h.y);
    float pa0 = half ? 0.f : sl, pa1 = half ? 0.f : sh;
    float pb0 = half ? sl : 0.f, pb1 = half ? sh : 0.f;

#define GP(P0, P1, SE, SO) { \
    int _i = half ? (SO) : (SE); \
    unsigned _u = y1u[(size_t)_i * 32 + cl]; \
    union { unsigned u; __half2 h; } _c; _c.u = _u; \
    P0 += __half2float(_c.h.x); P1 += __half2float(_c.h.y); }

    for (int tA = 0; tA < lenA; tA += 8) {
        int4 i0 = *(const int4*)(csA + tA);        // s_load_dwordx4
        int4 i1 = *(const int4*)(csA + tA + 4);
        GP(pa0, pa1, i0.x, i0.y) GP(pa0, pa1, i0.z, i0.w)
        GP(pa0, pa1, i1.x, i1.y) GP(pa0, pa1, i1.z, i1.w)
    }
    for (int tB = 0; tB < lenB; tB += 8) {
        int4 i0 = *(const int4*)(csB + tB);
        int4 i1 = *(const int4*)(csB + tB + 4);
        GP(pb0, pb1, i0.x, i0.y) GP(pb0, pb1, i0.z, i0.w)
        GP(pb0, pb1, i1.x, i1.y) GP(pb0, pb1, i1.z, i1.w)
    }
#undef GP

    pa0 += __shfl_xor(pa0, 32); pa1 += __shfl_xor(pa1, 32);
    pb0 += __shfl_xor(pb0, 32); pb1 += __shfl_xor(pb1, 32);
    float a0 = half ? pb0 : pa0;
    float a1 = half ? pb1 : pa1;

    float dv = dinv[node];
    float2 bb = *(const float2*)(b1 + k2);
    float h0 = fmaxf(a0 * dv + bb.x, 0.f);
    float h1 = fmaxf(a1 * dv + bb.y, 0.f);

    float sum = 0.f;
#pragma unroll
    for (int t = 0; t < 32; t++) {
        float hh0 = __shfl(h0, t, 32);
        float hh1 = __shfl(h1, t, 32);
        sum += hh0 * W2[(2 * t) * CLS_F + cl] + hh1 * W2[(2 * t + 1) * CLS_F + cl];
    }
    y2h[(size_t)node * CLS_F + cl] = f2h(sum * dv);

    if (blockIdx.x == 0 && tid < 16)   // zero dummy row N for gather2 padding
        ((unsigned*)y2h)[(size_t)N_NODES * 16 + tid] = 0;
}

// ---------------------------------------------------------------------------
// gather2 v3: 4 nodes per wave, one node per phase; quarter-wave groups of 16
// lanes each process a different neighbor per step (dword = 2 fp16 feats per
// lane). Indices via s_load_dwordx4; reduce across groups with shfl_xor.
// ---------------------------------------------------------------------------
__global__ __launch_bounds__(256) void gather2_kernel(const int* __restrict__ off,
                                                      const int* __restrict__ endp,
                                                      const int* __restrict__ csr,
                                                      const unsigned short* __restrict__ y2h,
                                                      const float* __restrict__ dinv,
                                                      const float* __restrict__ b2,
                                                      float* __restrict__ out) {
    int tid = threadIdx.x;
    int wv = __builtin_amdgcn_readfirstlane(tid >> 6);
    int wave = blockIdx.x * 4 + wv;
    int n0 = wave * 4;
    int lane = tid & 63;
    int g = lane >> 4;
    int fl = lane & 15;
    int k2 = 2 * fl;
    const unsigned* y2u = (const unsigned*)y2h;

    int4 offs = *(const int4*)(off + n0);     // s_load_dwordx4 (16B aligned)
    int4 ends = *(const int4*)(endp + n0);

    float r0 = 0.f, r1 = 0.f;

#define QS(P0, P1, IV) { \
    int _i = (g == 0) ? (IV).x : (g == 1) ? (IV).y : (g == 2) ? (IV).z : (IV).w; \
    unsigned _u = y2u[(size_t)_i * 16 + fl]; \
    union { unsigned u; __half2 h; } _c; _c.u = _u; \
    P0 += __half2float(_c.h.x); P1 += __half2float(_c.h.y); }

#pragma unroll
    for (int q = 0; q < 4; q++) {
        int o = (q == 0) ? offs.x : (q == 1) ? offs.y : (q == 2) ? offs.z : offs.w;
        int e = (q == 0) ? ends.x : (q == 1) ? ends.y : (q == 2) ? ends.z : ends.w;
        const int* cs = csr + o;
        int len = e - o;                       // multiple of 8
        float p0 = 0.f, p1 = 0.f;
        for (int t = 0; t < len; t += 8) {
            int4 i0 = *(const int4*)(cs + t);
            int4 i1 = *(const int4*)(cs + t + 4);
            QS(p0, p1, i0) QS(p0, p1, i1)
        }
        p0 += __shfl_xor(p0, 32); p0 += __shfl_xor(p0, 16);
        p1 += __shfl_xor(p1, 32); p1 += __shfl_xor(p1, 16);
        if (g == q) { r0 = p0; r1 = p1; }
    }
#undef QS

    int node = n0 + g;
    unsigned su = y2u[(size_t)node * 16 + fl];     // self
    union { unsigned u; __half2 h; } sc; sc.u = su;
    r0 += __half2float(sc.h.x);
    r1 += __half2float(sc.h.y);
    float dv = dinv[node];
    float2 bb = *(const float2*)(b2 + k2);
    float2 o2;
    o2.x = r0 * dv + bb.x;
    o2.y = r1 * dv + bb.y;
    *(float2*)(out + (size_t)node * CLS_F + k2) = o2;
}

extern "C" void kernel_launch(void* const* d_in, const int* in_sizes, int n_in,
                              void* d_out, int out_size, void* d_ws, size_t ws_size,
                              hipStream_t stream) {
    const float* x  = (const float*)d_in[0];
    const int*   ei = (const int*)d_in[1];
    // d_in[2] = edge_attr, unused by GCNConv
    const float* W1 = (const float*)d_in[3];
    const float* b1 = (const float*)d_in[4];
    const float* W2 = (const float*)d_in[5];
    const float* b2 = (const float*)d_in[6];
    float* out = (float*)d_out;

    const int* src = ei;
    const int* dst = ei + N_EDGES;

    char* ws = (char*)d_ws;
    size_t npad = ((size_t)N_NODES * 4 + 255) / 256 * 256;
    float* dinv = (float*)ws;
    int*   off  = (int*)(ws + npad);
    int*   endp = (int*)(ws + 2 * npad);
    int*   bh   = (int*)(ws + 3 * npad);              // NVAL=50176 ints (~200 KB)
    int*   csr  = (int*)(ws + 3 * npad + 204800);     // NBKT*CAPB ints = 10.49 MB
    char*  rbase = (char*)csr + (size_t)NBKT * CAPB * 4;
    unsigned* bkt = (unsigned*)rbase;                 // 6.4 MB, dead after sort_bucket
    unsigned short* y1h = (unsigned short*)rbase;     // (N+1)*64 fp16 = 12.8 MB, aliases bkt
    unsigned short* y2h = (unsigned short*)(rbase + (size_t)(N_NODES + 1) * HID_F * 2);

    dim3 blk(256);
    bucketA_kernel  <<<dim3(NBLK), blk, 0, stream>>>(dst, bh);
    scan_hist_kernel<<<dim3(1), dim3(1024), 0, stream>>>(bh);
    bucketB_kernel  <<<dim3(NBLK), blk, 0, stream>>>(src, dst, bh, bkt);
    sort_bucket_kernel<<<dim3(NBKT), blk, 0, stream>>>(bh, bkt, csr, off, endp, dinv);
    xw1_kernel      <<<dim3((N_NODES + XBM - 1) / XBM), blk, 0, stream>>>(x, W1, dinv, y1h);
    gather1_fused_kernel<<<dim3(N_NODES / 8), blk, 0, stream>>>(off, endp, csr, y1h, dinv, W2, b1, y2h);
    gather2_kernel  <<<dim3(N_NODES / 16), blk, 0, stream>>>(off, endp, csr, y2h, dinv, b2, out);
}

// Round 2
// 250.968 us; speedup vs baseline: 1.0705x; 1.0349x over previous
//
#include <hip/hip_runtime.h>
#include <hip/hip_fp16.h>

#define N_NODES 100000
#define N_EDGES 1600000
#define IN_F 128
#define HID_F 64
#define CLS_F 32

#define NBKT 512                 // buckets of 196 dst nodes each
#define BKT_NODES 196
#define EPB 16384                // edges per partition block
#define NBLK 98                  // ceil(1600000/16384)
#define NVAL (NBKT * NBLK)       // 50176
#define CAPB 5120                // fixed padded csr region per bucket (mean ~3900, >16 sigma)

typedef short s8v __attribute__((ext_vector_type(8)));
typedef float f4v __attribute__((ext_vector_type(4)));

__device__ __forceinline__ unsigned short f2h(float f) {
    return __half_as_ushort(__float2half_rn(f));
}
__device__ __forceinline__ int packh2(float x, float y) {
    __half2 p = __floats2half2_rn(x, y);
    union { __half2 h; int i; } c; c.h = p; return c.i;
}
__device__ __forceinline__ void acc8(float* a, int4 v) {
    union { int4 i; __half2 h[4]; } c; c.i = v;
#pragma unroll
    for (int j = 0; j < 4; j++) {
        float2 f = __half22float2(c.h[j]);
        a[2 * j] += f.x;
        a[2 * j + 1] += f.y;
    }
}
__device__ __forceinline__ void acc4(float* a, int2 v) {
    union { int2 i; __half2 h[2]; } c; c.i = v;
#pragma unroll
    for (int j = 0; j < 2; j++) {
        float2 f = __half22float2(c.h[j]);
        a[2 * j] += f.x;
        a[2 * j + 1] += f.y;
    }
}

// ---------------------------------------------------------------------------
// CSR build: bucket histogram -> scan -> scatter -> per-bucket counting sort.
// Node segments padded to multiple of 8 with dummy index N_NODES (zero rows).
// ---------------------------------------------------------------------------

__global__ __launch_bounds__(256) void bucketA_kernel(const int* __restrict__ dst,
                                                      int* __restrict__ bh) {
    __shared__ int h[NBKT];
    for (int i = threadIdx.x; i < NBKT; i += 256) h[i] = 0;
    __syncthreads();
    int e0 = blockIdx.x * EPB;
    int e1 = min(e0 + EPB, N_EDGES);
    for (int e = e0 + threadIdx.x; e < e1; e += 256)
        atomicAdd(&h[dst[e] / BKT_NODES], 1);
    __syncthreads();
    for (int i = threadIdx.x; i < NBKT; i += 256)
        bh[i * NBLK + blockIdx.x] = h[i];
}

__global__ __launch_bounds__(1024) void scan_hist_kernel(int* __restrict__ bh) {
    __shared__ int wsum[16];
    const int CH = (NVAL + 1023) / 1024;   // 49
    int t = threadIdx.x;
    int base = t * CH;
    int v[CH];
    int local = 0;
#pragma unroll
    for (int i = 0; i < CH; i++) {
        int idx = base + i;
        int x = (idx < NVAL) ? bh[idx] : 0;
        v[i] = local;
        local += x;
    }
    int lane = t & 63, w = t >> 6;
    int s = local;
#pragma unroll
    for (int d = 1; d < 64; d <<= 1) {
        int u = __shfl_up(s, d);
        if (lane >= d) s += u;
    }
    if (lane == 63) wsum[w] = s;
    __syncthreads();
    int wbase = 0;
    for (int i = 0; i < w; i++) wbase += wsum[i];
    int tbase = wbase + s - local;
#pragma unroll
    for (int i = 0; i < CH; i++) {
        int idx = base + i;
        if (idx < NVAL) bh[idx] = tbase + v[i];
    }
}

__global__ __launch_bounds__(256) void bucketB_kernel(const int* __restrict__ src,
                                                      const int* __restrict__ dst,
                                                      const int* __restrict__ bhScan,
                                                      unsigned* __restrict__ bkt) {
    __shared__ int cur[NBKT];
    for (int i = threadIdx.x; i < NBKT; i += 256)
        cur[i] = bhScan[i * NBLK + blockIdx.x];
    __syncthreads();
    int e0 = blockIdx.x * EPB;
    int e1 = min(e0 + EPB, N_EDGES);
    for (int e = e0 + threadIdx.x; e < e1; e += 256) {
        int d = dst[e];
        int g = d / BKT_NODES;
        unsigned pk = ((unsigned)(d - g * BKT_NODES) << 17) | (unsigned)src[e];
        int pos = atomicAdd(&cur[g], 1);
        bkt[pos] = pk;
    }
}

__global__ __launch_bounds__(256) void sort_bucket_kernel(const int* __restrict__ bhScan,
                                                          const unsigned* __restrict__ bkt,
                                                          int* __restrict__ csr,
                                                          int* __restrict__ off,
                                                          int* __restrict__ endp,
                                                          float* __restrict__ dinv) {
    __shared__ int hist[BKT_NODES];
    __shared__ int loff[BKT_NODES];    // mutated by scatter atomics
    __shared__ int loffB[BKT_NODES];   // stable padded bases
    __shared__ int wt[4];
    __shared__ int csrS[CAPB];
    int b = blockIdx.x;
    int t = threadIdx.x;
    int s0 = bhScan[b * NBLK];
    int s1 = (b < NBKT - 1) ? bhScan[(b + 1) * NBLK] : N_EDGES;
    int nE = s1 - s0;

    for (int i = t; i < BKT_NODES; i += 256) hist[i] = 0;
    __syncthreads();
    for (int i = t; i < nE; i += 256)
        atomicAdd(&hist[bkt[s0 + i] >> 17], 1);
    __syncthreads();

    // exclusive scan of PADDED per-node sizes (pad to multiple of 8)
    int h0 = 0, h1 = 0;
    if (t < 98) { h0 = hist[2 * t]; h1 = hist[2 * t + 1]; }
    int p0 = (h0 + 7) & ~7;
    int p1 = (h1 + 7) & ~7;
    int sum = p0 + p1;
    int lane = t & 63, w = t >> 6;
    int s = sum;
#pragma unroll
    for (int d = 1; d < 64; d <<= 1) {
        int u = __shfl_up(s, d);
        if (lane >= d) s += u;
    }
    if (lane == 63) wt[w] = s;
    __syncthreads();
    int wbase = 0;
    for (int i = 0; i < w; i++) wbase += wt[i];
    int excl = wbase + s - sum;
    if (t < 98) {
        loff[2 * t] = excl;         loffB[2 * t] = excl;
        loff[2 * t + 1] = excl + p0; loffB[2 * t + 1] = excl + p0;
    }
    __syncthreads();

    for (int j = t; j < BKT_NODES; j += 256) {
        int n = b * BKT_NODES + j;
        if (n < N_NODES) {
            int c = hist[j];
            int o = b * CAPB + loff[j];
            off[n] = o;
            endp[n] = o + ((c + 7) & ~7);          // padded length
            dinv[n] = rsqrtf((float)(c + 1));
        }
    }
    __syncthreads();

    // scatter into padded staging
    for (int i = t; i < nE; i += 256) {
        unsigned pk = bkt[s0 + i];
        int dl = (int)(pk >> 17);
        int p = atomicAdd(&loff[dl], 1);
        csrS[p] = (int)(pk & 0x1FFFFu);
    }
    __syncthreads();

    // fill pad slots with dummy node id (zero feature row)
    for (int j = t; j < BKT_NODES; j += 256) {
        int c = hist[j];
        int bse = loffB[j];
        int pe = bse + ((c + 7) & ~7);
        for (int p = bse + c; p < pe; p++) csrS[p] = N_NODES;
    }
    __syncthreads();

    int padTot = wt[0] + wt[1] + wt[2] + wt[3];
    for (int i = t; i < padTot; i += 256) csr[b * CAPB + i] = csrS[i];
}

// ---------------------------------------------------------------------------
// layer 1 GEMM via MFMA f16 (was bf16; f16 has 8x finer mantissa, same rate).
// y1 = (x @ W1) * dinv, fp16 rows of 128 B; row N_NODES written as zeros.
// ---------------------------------------------------------------------------
#define XBM 64
__global__ __launch_bounds__(256) void xw1_kernel(const float* __restrict__ x,
                                                  const float* __restrict__ W1,
                                                  const float* __restrict__ dinv,
                                                  unsigned short* __restrict__ y1h) {
    __shared__ __align__(16) unsigned short Wb[16 * 64 * 8];   // 16 KB, B-frag packed
    __shared__ __align__(16) unsigned short xb[XBM][IN_F + 8]; // 17 KB

    int tid = threadIdx.x;

    for (int i = tid; i < IN_F * HID_F; i += 256) {
        int k = i >> 6, n = i & 63;
        int kc = k >> 5, kw = k & 31;
        int nt = n >> 4, nl = n & 15;
        int quad = kw >> 3, j = kw & 7;
        Wb[(((kc * 4 + nt) * 64) + quad * 16 + nl) * 8 + j] = f2h(W1[i]);
    }

    int nodeBase = blockIdx.x * XBM;
    {
        int snl = tid >> 2;
        int sk0 = (tid & 3) * 32;
        int n = nodeBase + snl;
#pragma unroll
        for (int kk = 0; kk < 32; kk += 4) {
            float4 v = make_float4(0.f, 0.f, 0.f, 0.f);
            if (n < N_NODES) v = *(const float4*)(x + (size_t)n * IN_F + sk0 + kk);
            ushort4 o;
            o.x = f2h(v.x); o.y = f2h(v.y); o.z = f2h(v.z); o.w = f2h(v.w);
            *(ushort4*)(&xb[snl][sk0 + kk]) = o;
        }
    }
    __syncthreads();

    int wave = tid >> 6, lane = tid & 63;
    int quad = lane >> 4, l15 = lane & 15;
    int rowBase = wave * 16;

    f4v acc[4];
#pragma unroll
    for (int i = 0; i < 4; i++) acc[i] = (f4v){0.f, 0.f, 0.f, 0.f};

#pragma unroll
    for (int kc = 0; kc < 4; kc++) {
        s8v a = *(const s8v*)(&xb[rowBase + l15][kc * 32 + quad * 8]);
#pragma unroll
        for (int nt = 0; nt < 4; nt++) {
            s8v b = *(const s8v*)(&Wb[((kc * 4 + nt) * 64 + lane) * 8]);
            acc[nt] = __builtin_amdgcn_mfma_f32_16x16x32_f16(a, b, acc[nt], 0, 0, 0);
        }
    }

    float dv[4];
    int n0 = nodeBase + rowBase + quad * 4;
#pragma unroll
    for (int r = 0; r < 4; r++)
        dv[r] = (n0 + r < N_NODES) ? dinv[n0 + r] : 0.f;
#pragma unroll
    for (int nt = 0; nt < 4; nt++) {
#pragma unroll
        for (int r = 0; r < 4; r++) {
            int n = n0 + r;
            if (n < N_NODES + 1)    // row N_NODES written as zeros (dv=0)
                y1h[(size_t)n * HID_F + nt * 16 + l15] = f2h(acc[nt][r] * dv[r]);
        }
    }
}

// ---------------------------------------------------------------------------
// gather1 v4: 2 nodes per wave; 8 lanes per edge, dwordx4 per lane -> one
// wave-wide load covers 8 edges (full 128B rows). Lane g=lane>>3 reads its
// own csr index (8 lanes share a dword, coalesced); f=lane&7 owns feats
// 8f..8f+7. A/B loops merged for 2 independent load chains. Index prefetch
// 1 iteration ahead. Output: h = relu(agg*dinv + b1) as fp16 (W2 deferred
// to y2_kernel by linearity).
// ---------------------------------------------------------------------------
__global__ __launch_bounds__(256) void gather1_kernel(
        const int* __restrict__ off, const int* __restrict__ endp,
        const int* __restrict__ csr, const unsigned short* __restrict__ y1h,
        const float* __restrict__ dinv, const float* __restrict__ b1,
        unsigned short* __restrict__ hout) {
    int tid = threadIdx.x;
    int wv = __builtin_amdgcn_readfirstlane(tid >> 6);
    int wave = blockIdx.x * 4 + wv;
    int nA = wave * 2, nB = nA + 1;
    int lane = tid & 63;
    int f = lane & 7;
    int g = lane >> 3;
    int fo = f * 16;

    int offA = off[nA], offB = off[nB];
    int lenA = endp[nA] - offA, lenB = endp[nB] - offB;
    const int* pA = csr + offA + g;
    const int* pB = csr + offB + g;
    const char* yb = (const char*)y1h;

    float aA[8], aB[8];
#pragma unroll
    for (int j = 0; j < 8; j++) { aA[j] = 0.f; aB[j] = 0.f; }

    int lmin = min(lenA, lenB);
    int iA = pA[0], iB = pB[0];
    int t = 0;
    for (; t < lmin; t += 8) {
        int icA = iA, icB = iB;
        iA = pA[t + 8]; iB = pB[t + 8];
        int4 vA = *(const int4*)(yb + (size_t)icA * 128 + fo);
        int4 vB = *(const int4*)(yb + (size_t)icB * 128 + fo);
        acc8(aA, vA); acc8(aB, vB);
    }
    for (; t < lenA; t += 8) {
        int ic = iA; iA = pA[t + 8];
        int4 v = *(const int4*)(yb + (size_t)ic * 128 + fo);
        acc8(aA, v);
    }
    for (int u = lmin; u < lenB; u += 8) {
        int ic = iB; iB = pB[u + 8];
        int4 v = *(const int4*)(yb + (size_t)ic * 128 + fo);
        acc8(aB, v);
    }

    // butterfly reduce over the 8 edge-slot groups (lane bits 3,4,5)
#pragma unroll
    for (int m = 8; m <= 32; m <<= 1) {
#pragma unroll
        for (int j = 0; j < 8; j++) {
            aA[j] += __shfl_xor(aA[j], m);
            aB[j] += __shfl_xor(aB[j], m);
        }
    }

    // self loops (each lane adds its own f-slice once, post-reduce)
    int4 sA = *(const int4*)(yb + (size_t)nA * 128 + fo);
    int4 sB = *(const int4*)(yb + (size_t)nB * 128 + fo);
    acc8(aA, sA); acc8(aB, sB);

    float dvA = dinv[nA], dvB = dinv[nB];
    float4 bl = *(const float4*)(b1 + 8 * f);
    float4 bh4 = *(const float4*)(b1 + 8 * f + 4);
    float bb[8] = {bl.x, bl.y, bl.z, bl.w, bh4.x, bh4.y, bh4.z, bh4.w};
    float hA[8], hB[8];
#pragma unroll
    for (int j = 0; j < 8; j++) {
        hA[j] = fmaxf(aA[j] * dvA + bb[j], 0.f);
        hB[j] = fmaxf(aB[j] * dvB + bb[j], 0.f);
    }
    int4 HA, HB;
    HA.x = packh2(hA[0], hA[1]); HA.y = packh2(hA[2], hA[3]);
    HA.z = packh2(hA[4], hA[5]); HA.w = packh2(hA[6], hA[7]);
    HB.x = packh2(hB[0], hB[1]); HB.y = packh2(hB[2], hB[3]);
    HB.z = packh2(hB[4], hB[5]); HB.w = packh2(hB[6], hB[7]);

    if (lane < 16) {
        int node = (lane < 8) ? nA : nB;
        int4 hv = (lane < 8) ? HA : HB;
        *(int4*)((char*)hout + (size_t)node * 128 + (lane & 7) * 16) = hv;
    }
}

// ---------------------------------------------------------------------------
// y2 = (h @ W2) * dinv via MFMA f16: 100K x 64 x 32. 64 nodes per block.
// Row N_NODES written as zeros (dummy target for gather2 padding).
// ---------------------------------------------------------------------------
#define YBM 64
__global__ __launch_bounds__(256) void y2_kernel(const unsigned short* __restrict__ h,
                                                 const float* __restrict__ W2,
                                                 const float* __restrict__ dinv,
                                                 unsigned short* __restrict__ y2h) {
    __shared__ __align__(16) unsigned short Wb[2 * 2 * 64 * 8];  // 4 KB
    __shared__ __align__(16) unsigned short hb[YBM][HID_F + 8];  // 9 KB
    int tid = threadIdx.x;

    for (int i = tid; i < HID_F * CLS_F; i += 256) {
        int k = i >> 5, n = i & 31;
        int kc = k >> 5, kw = k & 31;
        int nt = n >> 4, nl = n & 15;
        int quad = kw >> 3, j = kw & 7;
        Wb[(((kc * 2 + nt) * 64) + quad * 16 + nl) * 8 + j] = f2h(W2[i]);
    }

    int nodeBase = blockIdx.x * YBM;
    {
        int row = tid >> 2, sseg = tid & 3;
        int n = nodeBase + row;
        int4 v0 = {0, 0, 0, 0}, v1 = {0, 0, 0, 0};
        if (n < N_NODES) {
            const char* hp = (const char*)h + (size_t)n * 128 + sseg * 32;
            v0 = *(const int4*)hp;
            v1 = *(const int4*)(hp + 16);
        }
        *(int4*)(&hb[row][sseg * 16]) = v0;
        *(int4*)(&hb[row][sseg * 16 + 8]) = v1;
    }
    __syncthreads();

    int wave = tid >> 6, lane = tid & 63;
    int quad = lane >> 4, l15 = lane & 15;
    int rowBase = wave * 16;

    f4v acc[2];
#pragma unroll
    for (int i = 0; i < 2; i++) acc[i] = (f4v){0.f, 0.f, 0.f, 0.f};

#pragma unroll
    for (int kc = 0; kc < 2; kc++) {
        s8v a = *(const s8v*)(&hb[rowBase + l15][kc * 32 + quad * 8]);
#pragma unroll
        for (int nt = 0; nt < 2; nt++) {
            s8v b = *(const s8v*)(&Wb[((kc * 2 + nt) * 64 + lane) * 8]);
            acc[nt] = __builtin_amdgcn_mfma_f32_16x16x32_f16(a, b, acc[nt], 0, 0, 0);
        }
    }

    float dv[4];
    int n0 = nodeBase + rowBase + quad * 4;
#pragma unroll
    for (int r = 0; r < 4; r++)
        dv[r] = (n0 + r < N_NODES) ? dinv[n0 + r] : 0.f;
#pragma unroll
    for (int nt = 0; nt < 2; nt++) {
#pragma unroll
        for (int r = 0; r < 4; r++) {
            int n = n0 + r;
            if (n < N_NODES + 1)
                y2h[(size_t)n * CLS_F + nt * 16 + l15] = f2h(acc[nt][r] * dv[r]);
        }
    }
}

// ---------------------------------------------------------------------------
// gather2 v4: same structure as gather1 v4; rows are 64 B (32 fp16), so
// dwordx2 per lane, 8 lanes per edge, 8 edges per wave-wide load.
// out = (sum y2[nbr] + y2[self]) * dinv + b2, f32.
// ---------------------------------------------------------------------------
__global__ __launch_bounds__(256) void gather2_kernel(const int* __restrict__ off,
                                                      const int* __restrict__ endp,
                                                      const int* __restrict__ csr,
                                                      const unsigned short* __restrict__ y2h,
                                                      const float* __restrict__ dinv,
                                                      const float* __restrict__ b2,
                                                      float* __restrict__ out) {
    int tid = threadIdx.x;
    int wv = __builtin_amdgcn_readfirstlane(tid >> 6);
    int wave = blockIdx.x * 4 + wv;
    int nA = wave * 2, nB = nA + 1;
    int lane = tid & 63;
    int f = lane & 7;
    int g = lane >> 3;
    int fo = f * 8;

    int offA = off[nA], offB = off[nB];
    int lenA = endp[nA] - offA, lenB = endp[nB] - offB;
    const int* pA = csr + offA + g;
    const int* pB = csr + offB + g;
    const char* yb = (const char*)y2h;

    float aA[4], aB[4];
#pragma unroll
    for (int j = 0; j < 4; j++) { aA[j] = 0.f; aB[j] = 0.f; }

    int lmin = min(lenA, lenB);
    int iA = pA[0], iB = pB[0];
    int t = 0;
    for (; t < lmin; t += 8) {
        int icA = iA, icB = iB;
        iA = pA[t + 8]; iB = pB[t + 8];
        int2 vA = *(const int2*)(yb + (size_t)icA * 64 + fo);
        int2 vB = *(const int2*)(yb + (size_t)icB * 64 + fo);
        acc4(aA, vA); acc4(aB, vB);
    }
    for (; t < lenA; t += 8) {
        int ic = iA; iA = pA[t + 8];
        int2 v = *(const int2*)(yb + (size_t)ic * 64 + fo);
        acc4(aA, v);
    }
    for (int u = lmin; u < lenB; u += 8) {
        int ic = iB; iB = pB[u + 8];
        int2 v = *(const int2*)(yb + (size_t)ic * 64 + fo);
        acc4(aB, v);
    }

#pragma unroll
    for (int m = 8; m <= 32; m <<= 1) {
#pragma unroll
        for (int j = 0; j < 4; j++) {
            aA[j] += __shfl_xor(aA[j], m);
            aB[j] += __shfl_xor(aB[j], m);
        }
    }

    // self loops
    int2 sA = *(const int2*)(yb + (size_t)nA * 64 + fo);
    int2 sB = *(const int2*)(yb + (size_t)nB * 64 + fo);
    acc4(aA, sA); acc4(aB, sB);

    float dvA = dinv[nA], dvB = dinv[nB];
    float4 b2v = *(const float4*)(b2 + 4 * f);
    float bbv[4] = {b2v.x, b2v.y, b2v.z, b2v.w};
    float4 oA, oB;
    float* oAp = (float*)&oA;
    float* oBp = (float*)&oB;
#pragma unroll
    for (int j = 0; j < 4; j++) {
        oAp[j] = aA[j] * dvA + bbv[j];
        oBp[j] = aB[j] * dvB + bbv[j];
    }
    if (lane < 16) {
        int node = (lane < 8) ? nA : nB;
        float4 ov = (lane < 8) ? oA : oB;
        *(float4*)(out + (size_t)node * CLS_F + (lane & 7) * 4) = ov;
    }
}

extern "C" void kernel_launch(void* const* d_in, const int* in_sizes, int n_in,
                              void* d_out, int out_size, void* d_ws, size_t ws_size,
                              hipStream_t stream) {
    const float* x  = (const float*)d_in[0];
    const int*   ei = (const int*)d_in[1];
    // d_in[2] = edge_attr, unused by GCNConv
    const float* W1 = (const float*)d_in[3];
    const float* b1 = (const float*)d_in[4];
    const float* W2 = (const float*)d_in[5];
    const float* b2 = (const float*)d_in[6];
    float* out = (float*)d_out;

    const int* src = ei;
    const int* dst = ei + N_EDGES;

    char* ws = (char*)d_ws;
    size_t npad = ((size_t)N_NODES * 4 + 255) / 256 * 256;
    float* dinv = (float*)ws;
    int*   off  = (int*)(ws + npad);
    int*   endp = (int*)(ws + 2 * npad);
    int*   bh   = (int*)(ws + 3 * npad);              // NVAL=50176 ints (~200 KB)
    int*   csr  = (int*)(ws + 3 * npad + 204800);     // NBKT*CAPB ints = 10.49 MB
    char*  rbase = (char*)csr + (size_t)NBKT * CAPB * 4;
    unsigned* bkt = (unsigned*)rbase;                 // 6.4 MB, dead after sort_bucket
    unsigned short* y1h = (unsigned short*)rbase;     // (N+1)*64 fp16 = 12.8 MB, aliases bkt
    unsigned short* y2h = (unsigned short*)(rbase + (size_t)(N_NODES + 1) * HID_F * 2);  // 6.4 MB
    unsigned short* hbuf = (unsigned short*)((char*)y2h + (size_t)(N_NODES + 1) * CLS_F * 2); // 12.8 MB

    dim3 blk(256);
    bucketA_kernel  <<<dim3(NBLK), blk, 0, stream>>>(dst, bh);
    scan_hist_kernel<<<dim3(1), dim3(1024), 0, stream>>>(bh);
    bucketB_kernel  <<<dim3(NBLK), blk, 0, stream>>>(src, dst, bh, bkt);
    sort_bucket_kernel<<<dim3(NBKT), blk, 0, stream>>>(bh, bkt, csr, off, endp, dinv);
    xw1_kernel      <<<dim3((N_NODES + XBM - 1) / XBM), blk, 0, stream>>>(x, W1, dinv, y1h);
    gather1_kernel  <<<dim3(N_NODES / 8), blk, 0, stream>>>(off, endp, csr, y1h, dinv, b1, hbuf);
    y2_kernel       <<<dim3((N_NODES + YBM) / YBM), blk, 0, stream>>>(hbuf, W2, dinv, y2h);
    gather2_kernel  <<<dim3(N_NODES / 8), blk, 0, stream>>>(off, endp, csr, y2h, dinv, b2, out);
}